// Round 1
// baseline (657.905 us; speedup 1.0000x reference)
//
#include <hip/hip_runtime.h>

#define E_TOTAL 500000
#define NNODES  100000
#define HID     128
#define K1      384

typedef __bf16 bf16x8 __attribute__((ext_vector_type(8)));
typedef float  f32x4  __attribute__((ext_vector_type(4)));

// Pack W [K][128] (fp32 row-major) into bf16 MFMA-B-fragment order:
// tile (kstep, nt): lane l = q*16 + n15 holds W[kstep*32 + q*8 + j][nt*16 + n15], j=0..7
__global__ void pack_w_kernel(const float* __restrict__ W, __bf16* __restrict__ out, int K) {
    int idx = blockIdx.x * 256 + threadIdx.x;
    if (idx >= K * 128) return;
    int k = idx >> 7, nn = idx & 127;
    int kstep = k >> 5, q = (k >> 3) & 3, j = k & 7;
    int nt = nn >> 4, n15 = nn & 15;
    int lane = q * 16 + n15;
    out[(((kstep * 8 + nt) * 64 + lane) << 3) + j] = (__bf16)W[idx];
}

__launch_bounds__(256, 2)
__global__ void edge_mlp_kernel(
    const float* __restrict__ x,
    const int*   __restrict__ eidx,   // [2*E]: src then dst
    const float* __restrict__ edge,
    const float* __restrict__ b1, const float* __restrict__ g1, const float* __restrict__ be1,
    const float* __restrict__ b2, const float* __restrict__ g2, const float* __restrict__ be2,
    const __bf16* __restrict__ w1f, const __bf16* __restrict__ w2f,
    float* __restrict__ out)
{
    // h1 tile: [wave][row 0..63][128 cols], 16B-block XOR swizzle to kill A2-read conflicts
    __shared__ __align__(16) __bf16 h1s[4][64][128];

    const int tid  = threadIdx.x;
    const int w    = tid >> 6;
    const int l    = tid & 63;
    const int q    = l >> 4;     // quad
    const int n15  = l & 15;
    const int ebase = blockIdx.x * 256 + w * 64;

    // Per-mtile row pointers for the gather (row m = lane&15 within each mtile)
    const float* psrc[4]; const float* pdst[4]; const float* pedg[4];
    #pragma unroll
    for (int mt = 0; mt < 4; ++mt) {
        int e  = ebase + mt * 16 + n15;
        int ec = e < E_TOTAL ? e : (E_TOTAL - 1);
        int s  = eidx[ec];
        int d  = eidx[E_TOTAL + ec];
        psrc[mt] = x + (size_t)s * HID;
        pdst[mt] = x + (size_t)d * HID;
        pedg[mt] = edge + (size_t)ec * HID;
    }

    f32x4 acc[4][8];
    #pragma unroll
    for (int mt = 0; mt < 4; ++mt)
        #pragma unroll
        for (int nt = 0; nt < 8; ++nt) {
            f32x4 z = {0.f, 0.f, 0.f, 0.f};
            acc[mt][nt] = z;
        }

    // ---- GEMM1: [64 edges x 384] @ W1[384 x 128] ----
    #pragma unroll
    for (int ks = 0; ks < 12; ++ks) {
        bf16x8 a[4];
        #pragma unroll
        for (int mt = 0; mt < 4; ++mt) {
            const float* base =
                (ks < 4) ? (psrc[mt] + ks * 32) :
                (ks < 8) ? (pdst[mt] + (ks - 4) * 32) :
                           (pedg[mt] + (ks - 8) * 32);
            base += q * 8;
            float4 v0 = *reinterpret_cast<const float4*>(base);
            float4 v1 = *reinterpret_cast<const float4*>(base + 4);
            bf16x8 t;
            t[0]=(__bf16)v0.x; t[1]=(__bf16)v0.y; t[2]=(__bf16)v0.z; t[3]=(__bf16)v0.w;
            t[4]=(__bf16)v1.x; t[5]=(__bf16)v1.y; t[6]=(__bf16)v1.z; t[7]=(__bf16)v1.w;
            a[mt] = t;
        }
        const bf16x8* wf = reinterpret_cast<const bf16x8*>(w1f) + (size_t)(ks * 8) * 64 + l;
        #pragma unroll
        for (int nt = 0; nt < 8; ++nt) {
            bf16x8 b = wf[nt * 64];
            #pragma unroll
            for (int mt = 0; mt < 4; ++mt)
                acc[mt][nt] = __builtin_amdgcn_mfma_f32_16x16x32_bf16(a[mt], b, acc[mt][nt], 0, 0, 0);
        }
    }

    // ---- Epilogue 1: +b1, LN(g1,be1), SiLU, store bf16 to LDS (A-layout source) ----
    {
        float b1v[8], g1v[8], be1v[8];
        #pragma unroll
        for (int nt = 0; nt < 8; ++nt) {
            int c = nt * 16 + n15;
            b1v[nt] = b1[c]; g1v[nt] = g1[c]; be1v[nt] = be1[c];
        }
        #pragma unroll
        for (int mt = 0; mt < 4; ++mt) {
            float sm[4] = {0,0,0,0}, sq[4] = {0,0,0,0};
            #pragma unroll
            for (int nt = 0; nt < 8; ++nt)
                #pragma unroll
                for (int r = 0; r < 4; ++r) {
                    float v = acc[mt][nt][r] + b1v[nt];
                    acc[mt][nt][r] = v;
                    sm[r] += v; sq[r] += v * v;
                }
            #pragma unroll
            for (int o = 1; o < 16; o <<= 1)
                #pragma unroll
                for (int r = 0; r < 4; ++r) {
                    sm[r] += __shfl_xor(sm[r], o, 64);
                    sq[r] += __shfl_xor(sq[r], o, 64);
                }
            #pragma unroll
            for (int r = 0; r < 4; ++r) {
                float mu  = sm[r] * (1.f / 128.f);
                float var = sq[r] * (1.f / 128.f) - mu * mu;
                float rs  = rsqrtf(var + 1e-5f);
                int row = mt * 16 + q * 4 + r;
                #pragma unroll
                for (int nt = 0; nt < 8; ++nt) {
                    float v = (acc[mt][nt][r] - mu) * rs * g1v[nt] + be1v[nt];
                    float h = v * (1.f / (1.f + __expf(-v)));   // SiLU
                    int col = nt * 16 + n15;
                    int cb  = (col >> 3) ^ (row & 7);           // XOR swizzle, 16B blocks
                    h1s[w][row][cb * 8 + (col & 7)] = (__bf16)h;
                }
            }
        }
    }
    __syncthreads();

    // ---- GEMM2: h1[64 x 128] @ W2[128 x 128] ----
    #pragma unroll
    for (int mt = 0; mt < 4; ++mt)
        #pragma unroll
        for (int nt = 0; nt < 8; ++nt) {
            f32x4 z = {0.f, 0.f, 0.f, 0.f};
            acc[mt][nt] = z;
        }
    #pragma unroll
    for (int ks = 0; ks < 4; ++ks) {
        bf16x8 a[4];
        #pragma unroll
        for (int mt = 0; mt < 4; ++mt) {
            int row = mt * 16 + n15;          // A row = lane&15
            int kb  = ks * 4 + q;             // 16B block of k0 = ks*32 + q*8
            int cb  = kb ^ (row & 7);
            a[mt] = *reinterpret_cast<const bf16x8*>(&h1s[w][row][cb * 8]);
        }
        const bf16x8* wf = reinterpret_cast<const bf16x8*>(w2f) + (size_t)(ks * 8) * 64 + l;
        #pragma unroll
        for (int nt = 0; nt < 8; ++nt) {
            bf16x8 b = wf[nt * 64];
            #pragma unroll
            for (int mt = 0; mt < 4; ++mt)
                acc[mt][nt] = __builtin_amdgcn_mfma_f32_16x16x32_bf16(a[mt], b, acc[mt][nt], 0, 0, 0);
        }
    }

    // ---- Epilogue 2: +b2, LN(g2,be2), tanh, residual add, store ----
    {
        float b2v[8], g2v[8], be2v[8];
        #pragma unroll
        for (int nt = 0; nt < 8; ++nt) {
            int c = nt * 16 + n15;
            b2v[nt] = b2[c]; g2v[nt] = g2[c]; be2v[nt] = be2[c];
        }
        #pragma unroll
        for (int mt = 0; mt < 4; ++mt) {
            float sm[4] = {0,0,0,0}, sq[4] = {0,0,0,0};
            #pragma unroll
            for (int nt = 0; nt < 8; ++nt)
                #pragma unroll
                for (int r = 0; r < 4; ++r) {
                    float v = acc[mt][nt][r] + b2v[nt];
                    acc[mt][nt][r] = v;
                    sm[r] += v; sq[r] += v * v;
                }
            #pragma unroll
            for (int o = 1; o < 16; o <<= 1)
                #pragma unroll
                for (int r = 0; r < 4; ++r) {
                    sm[r] += __shfl_xor(sm[r], o, 64);
                    sq[r] += __shfl_xor(sq[r], o, 64);
                }
            #pragma unroll
            for (int r = 0; r < 4; ++r) {
                float mu  = sm[r] * (1.f / 128.f);
                float var = sq[r] * (1.f / 128.f) - mu * mu;
                float rs  = rsqrtf(var + 1e-5f);
                int e = ebase + mt * 16 + q * 4 + r;
                if (e < E_TOTAL) {
                    #pragma unroll
                    for (int nt = 0; nt < 8; ++nt) {
                        float v = (acc[mt][nt][r] - mu) * rs * g2v[nt] + be2v[nt];
                        float tv = fminf(fmaxf(v, -15.f), 15.f);
                        float ex = __expf(2.f * tv);
                        float th = (ex - 1.f) / (ex + 1.f);    // tanh
                        size_t off = (size_t)e * HID + nt * 16 + n15;
                        out[off] = edge[off] + th;
                    }
                }
            }
        }
    }
}

extern "C" void kernel_launch(void* const* d_in, const int* in_sizes, int n_in,
                              void* d_out, int out_size, void* d_ws, size_t ws_size,
                              hipStream_t stream) {
    const float* x   = (const float*)d_in[0];
    const int*   ei  = (const int*)d_in[1];
    const float* edge= (const float*)d_in[2];
    const float* W1  = (const float*)d_in[3];
    const float* b1  = (const float*)d_in[4];
    const float* g1  = (const float*)d_in[5];
    const float* be1 = (const float*)d_in[6];
    const float* W2  = (const float*)d_in[7];
    const float* b2  = (const float*)d_in[8];
    const float* g2  = (const float*)d_in[9];
    const float* be2 = (const float*)d_in[10];
    float* out = (float*)d_out;

    __bf16* w1f = (__bf16*)d_ws;                 // 384*128 bf16 = 96 KB
    __bf16* w2f = w1f + K1 * HID;                // 128*128 bf16 = 32 KB

    pack_w_kernel<<<(K1 * HID + 255) / 256, 256, 0, stream>>>(W1, w1f, K1);
    pack_w_kernel<<<(HID * HID + 255) / 256, 256, 0, stream>>>(W2, w2f, HID);

    int nblk = (E_TOTAL + 255) / 256;
    edge_mlp_kernel<<<nblk, 256, 0, stream>>>(x, ei, edge,
                                              b1, g1, be1, b2, g2, be2,
                                              w1f, w2f, out);
}